// Round 2
// baseline (1375.909 us; speedup 1.0000x reference)
//
#include <hip/hip_runtime.h>
#include <math.h>

// GCN 2-layer fused pipeline for MI355X.
// Layer1 input is [N,1] so aggregation collapses to scalar; layer2 is 2-wide.
// edge_index arrives as int32 (JAX x64-disabled downcasts int64 -> int32;
// harness: integer -> const int*).
// ws layout (floats): deg[N] | dinv[N] | s1[N] | t0[N] | t1[N] | o0[N] | o1[N]

__global__ void deg_kernel(const int* __restrict__ dst, float* __restrict__ deg, int E) {
    int e = blockIdx.x * blockDim.x + threadIdx.x;
    if (e < E) {
        atomicAdd(&deg[dst[e]], 1.0f);
    }
}

// dinv[i] = rsqrt(deg[i] + 1) (self loop); s1 initialized with self-loop term.
__global__ void dinv_kernel(const float* __restrict__ deg, const float* __restrict__ x,
                            float* __restrict__ dinv, float* __restrict__ s1, int N) {
    int i = blockIdx.x * blockDim.x + threadIdx.x;
    if (i < N) {
        float di = rsqrtf(deg[i] + 1.0f);
        dinv[i] = di;
        s1[i] = di * di * x[i];
    }
}

// s1[dst] += dinv[src]*dinv[dst]*x[src]
__global__ void agg1_kernel(const int* __restrict__ src, const int* __restrict__ dst,
                            const float* __restrict__ x, const float* __restrict__ dinv,
                            float* __restrict__ s1, int E) {
    int e = blockIdx.x * blockDim.x + threadIdx.x;
    if (e < E) {
        int s = src[e];
        int d = dst[e];
        float w = dinv[s] * dinv[d] * x[s];
        atomicAdd(&s1[d], w);
    }
}

// Per-node: h1 = relu(s1*W1 + b1) [32]; t = h1 @ W2 [2]; o = dinv^2 * t (self loop init)
__global__ void node_mlp_kernel(const float* __restrict__ s1, const float* __restrict__ dinv,
                                const float* __restrict__ W1, const float* __restrict__ b1,
                                const float* __restrict__ W2,
                                float* __restrict__ t0, float* __restrict__ t1,
                                float* __restrict__ o0, float* __restrict__ o1, int N) {
    __shared__ float sW1[32], sb1[32], sW2[64];
    int t = threadIdx.x;
    if (t < 32) { sW1[t] = W1[t]; sb1[t] = b1[t]; }
    if (t < 64) { sW2[t] = W2[t]; }
    __syncthreads();
    int i = blockIdx.x * blockDim.x + t;
    if (i < N) {
        float s = s1[i];
        float a0 = 0.0f, a1 = 0.0f;
#pragma unroll
        for (int j = 0; j < 32; ++j) {
            float h = fmaxf(fmaf(s, sW1[j], sb1[j]), 0.0f);
            a0 = fmaf(h, sW2[2 * j], a0);
            a1 = fmaf(h, sW2[2 * j + 1], a1);
        }
        t0[i] = a0;
        t1[i] = a1;
        float di = dinv[i];
        float d2 = di * di;
        o0[i] = d2 * a0;
        o1[i] = d2 * a1;
    }
}

// o[dst] += norm * t[src], 2-wide
__global__ void agg2_kernel(const int* __restrict__ src, const int* __restrict__ dst,
                            const float* __restrict__ dinv,
                            const float* __restrict__ t0, const float* __restrict__ t1,
                            float* __restrict__ o0, float* __restrict__ o1, int E) {
    int e = blockIdx.x * blockDim.x + threadIdx.x;
    if (e < E) {
        int s = src[e];
        int d = dst[e];
        float w = dinv[s] * dinv[d];
        atomicAdd(&o0[d], w * t0[s]);
        atomicAdd(&o1[d], w * t1[s]);
    }
}

// out[i] = log_softmax([o0+b2_0, o1+b2_1])
__global__ void logsoftmax_kernel(const float* __restrict__ o0, const float* __restrict__ o1,
                                  const float* __restrict__ b2, float* __restrict__ out, int N) {
    int i = blockIdx.x * blockDim.x + threadIdx.x;
    if (i < N) {
        float z0 = o0[i] + b2[0];
        float z1 = o1[i] + b2[1];
        float m = fmaxf(z0, z1);
        float mn = fminf(z0, z1);
        float l = m + logf(1.0f + __expf(mn - m));
        float2 r;
        r.x = z0 - l;
        r.y = z1 - l;
        ((float2*)out)[i] = r;
    }
}

extern "C" void kernel_launch(void* const* d_in, const int* in_sizes, int n_in,
                              void* d_out, int out_size, void* d_ws, size_t ws_size,
                              hipStream_t stream) {
    const float* x  = (const float*)d_in[0];
    const int* ei   = (const int*)d_in[1];     // int32! (JAX x64 disabled)
    const float* W1 = (const float*)d_in[2];
    const float* b1 = (const float*)d_in[3];
    const float* W2 = (const float*)d_in[4];
    const float* b2 = (const float*)d_in[5];
    float* out = (float*)d_out;

    const int N = in_sizes[0];       // x is [N,1]
    const int E = in_sizes[1] / 2;   // edge_index is [2,E]

    float* deg  = (float*)d_ws;
    float* dinv = deg + N;
    float* s1   = dinv + N;
    float* t0   = s1 + N;
    float* t1   = t0 + N;
    float* o0   = t1 + N;
    float* o1   = o0 + N;

    const int* src = ei;
    const int* dst = ei + E;

    hipMemsetAsync(deg, 0, (size_t)N * sizeof(float), stream);

    const int EB = 256;
    const int NB = 256;
    int eg = (E + EB - 1) / EB;
    int ng = (N + NB - 1) / NB;

    deg_kernel<<<eg, EB, 0, stream>>>(dst, deg, E);
    dinv_kernel<<<ng, NB, 0, stream>>>(deg, x, dinv, s1, N);
    agg1_kernel<<<eg, EB, 0, stream>>>(src, dst, x, dinv, s1, E);
    node_mlp_kernel<<<ng, NB, 0, stream>>>(s1, dinv, W1, b1, W2, t0, t1, o0, o1, N);
    agg2_kernel<<<eg, EB, 0, stream>>>(src, dst, dinv, t0, t1, o0, o1, E);
    logsoftmax_kernel<<<ng, NB, 0, stream>>>(o0, o1, b2, out, N);
}

// Round 3
// 1375.830 us; speedup vs baseline: 1.0001x; 1.0001x over previous
//
#include <hip/hip_runtime.h>
#include <math.h>

// GCN 2-layer, MI355X. Round 3: eliminate global atomics (20 G/s cap measured
// in R2: agg2 WRITE_SIZE 400 MB = 12.8M atomics x 32B) via bucketed-LDS
// aggregation. Nodes split into NBK buckets of BSZ=8192 so accumulators fit
// LDS; edges bucketized once as packed u32 (src<<13 | dst_local); each agg
// pass = sequential edge read + LDS atomics + coalesced partial writes +
// tree reduce. Global atomics: only ~5k block-level cursor reservations.

#define NBK     13
#define BSHIFT  13
#define BSZ     8192            // nodes per bucket
#define CAP     540672          // per-bucket edge capacity (exp 524288, +23 sigma)
#define R1REP   40              // replicas/bucket for deg & agg1 (grid 520)
#define R2REP   20              // replicas/bucket for agg2 (grid 260)
#define ABLK    512             // threads for bucket/agg kernels
#define ACHUNK  8192            // edges per bucketize block (16/thread)

// ---------------- fast path kernels ----------------

__global__ void bucketize_kernel(const int* __restrict__ src, const int* __restrict__ dst,
                                 unsigned* __restrict__ cursors, unsigned* __restrict__ ebuf,
                                 int E) {
    __shared__ unsigned cnt[NBK], base[NBK], run[NBK];
    int t = threadIdx.x;
    if (t < NBK) cnt[t] = 0;
    __syncthreads();
    int e0 = blockIdx.x * ACHUNK;
    int dd[16], ss[16];
#pragma unroll
    for (int k = 0; k < 16; ++k) {
        int e = e0 + k * ABLK + t;
        if (e < E) {
            dd[k] = dst[e];
            ss[k] = src[e];
            atomicAdd(&cnt[dd[k] >> BSHIFT], 1u);
        } else dd[k] = -1;
    }
    __syncthreads();
    if (t < NBK) { base[t] = atomicAdd(&cursors[t], cnt[t]); run[t] = 0; }
    __syncthreads();
#pragma unroll
    for (int k = 0; k < 16; ++k) {
        if (dd[k] >= 0) {
            int b = dd[k] >> BSHIFT;
            unsigned pos = base[b] + atomicAdd(&run[b], 1u);
            if (pos < (unsigned)CAP)
                ebuf[(size_t)b * CAP + pos] =
                    ((unsigned)ss[k] << BSHIFT) | (unsigned)(dd[k] & (BSZ - 1));
        }
    }
}

__global__ void b0_deg_kernel(const unsigned* __restrict__ ebuf,
                              const unsigned* __restrict__ cursors,
                              unsigned* __restrict__ part) {
    __shared__ unsigned acc[BSZ];
    int b = blockIdx.x / R1REP, r = blockIdx.x % R1REP;
    for (int j = threadIdx.x; j < BSZ; j += ABLK) acc[j] = 0;
    __syncthreads();
    unsigned c = cursors[b]; if (c > (unsigned)CAP) c = CAP;
    unsigned per = (c + R1REP - 1) / R1REP;
    unsigned i0 = r * per, i1 = i0 + per; if (i1 > c) i1 = c;
    const unsigned* eb = ebuf + (size_t)b * CAP;
    for (unsigned i = i0 + threadIdx.x; i < i1; i += ABLK)
        atomicAdd(&acc[eb[i] & (BSZ - 1)], 1u);
    __syncthreads();
    unsigned* p = part + (size_t)blockIdx.x * BSZ;
    for (int j = threadIdx.x; j < BSZ; j += ABLK) p[j] = acc[j];
}

__global__ void r0_kernel(const unsigned* __restrict__ part, const float* __restrict__ x,
                          float* __restrict__ dinv, float* __restrict__ xd, int N) {
    int i = blockIdx.x * blockDim.x + threadIdx.x;
    if (i >= N) return;
    int b = i >> BSHIFT, dl = i & (BSZ - 1);
    unsigned deg = 0;
    const unsigned* p = part + (size_t)(b * R1REP) * BSZ + dl;
#pragma unroll 4
    for (int r = 0; r < R1REP; ++r) deg += p[(size_t)r * BSZ];
    float di = rsqrtf((float)deg + 1.0f);
    dinv[i] = di;
    xd[i] = di * x[i];
}

__global__ void b1_agg1_kernel(const unsigned* __restrict__ ebuf,
                               const unsigned* __restrict__ cursors,
                               const float* __restrict__ xd,
                               float* __restrict__ part) {
    __shared__ float acc[BSZ];
    int b = blockIdx.x / R1REP, r = blockIdx.x % R1REP;
    for (int j = threadIdx.x; j < BSZ; j += ABLK) acc[j] = 0.0f;
    __syncthreads();
    unsigned c = cursors[b]; if (c > (unsigned)CAP) c = CAP;
    unsigned per = (c + R1REP - 1) / R1REP;
    unsigned i0 = r * per, i1 = i0 + per; if (i1 > c) i1 = c;
    const unsigned* eb = ebuf + (size_t)b * CAP;
    for (unsigned i = i0 + threadIdx.x; i < i1; i += ABLK) {
        unsigned pk = eb[i];
        atomicAdd(&acc[pk & (BSZ - 1)], xd[pk >> BSHIFT]);
    }
    __syncthreads();
    float* p = (float*)part + (size_t)blockIdx.x * BSZ;
    for (int j = threadIdx.x; j < BSZ; j += ABLK) p[j] = acc[j];
}

__global__ void r1_kernel(const float* __restrict__ part, const float* __restrict__ x,
                          const float* __restrict__ dinv,
                          const float* __restrict__ W1, const float* __restrict__ b1,
                          const float* __restrict__ W2,
                          float2* __restrict__ ttp, float* __restrict__ os0,
                          float* __restrict__ os1, int N) {
    __shared__ float sW1[32], sb1[32], sW2[64];
    int t = threadIdx.x;
    if (t < 32) { sW1[t] = W1[t]; sb1[t] = b1[t]; }
    if (t < 64) sW2[t] = W2[t];
    __syncthreads();
    int i = blockIdx.x * blockDim.x + t;
    if (i >= N) return;
    int b = i >> BSHIFT, dl = i & (BSZ - 1);
    float S = 0.0f;
    const float* p = part + (size_t)(b * R1REP) * BSZ + dl;
#pragma unroll 4
    for (int r = 0; r < R1REP; ++r) S += p[(size_t)r * BSZ];
    float di = dinv[i];
    float s1v = di * di * x[i] + di * S;
    float a0 = 0.0f, a1 = 0.0f;
#pragma unroll
    for (int j = 0; j < 32; ++j) {
        float h = fmaxf(fmaf(s1v, sW1[j], sb1[j]), 0.0f);
        a0 = fmaf(h, sW2[2 * j], a0);
        a1 = fmaf(h, sW2[2 * j + 1], a1);
    }
    ttp[i] = make_float2(di * a0, di * a1);
    os0[i] = di * di * a0;
    os1[i] = di * di * a1;
}

__global__ void b2_agg2_kernel(const unsigned* __restrict__ ebuf,
                               const unsigned* __restrict__ cursors,
                               const float2* __restrict__ ttp,
                               float* __restrict__ part) {
    __shared__ float a0[BSZ];
    __shared__ float a1[BSZ];
    int b = blockIdx.x / R2REP, r = blockIdx.x % R2REP;
    for (int j = threadIdx.x; j < BSZ; j += ABLK) { a0[j] = 0.0f; a1[j] = 0.0f; }
    __syncthreads();
    unsigned c = cursors[b]; if (c > (unsigned)CAP) c = CAP;
    unsigned per = (c + R2REP - 1) / R2REP;
    unsigned i0 = r * per, i1 = i0 + per; if (i1 > c) i1 = c;
    const unsigned* eb = ebuf + (size_t)b * CAP;
    for (unsigned i = i0 + threadIdx.x; i < i1; i += ABLK) {
        unsigned pk = eb[i];
        int dl = pk & (BSZ - 1);
        float2 v = ttp[pk >> BSHIFT];
        atomicAdd(&a0[dl], v.x);
        atomicAdd(&a1[dl], v.y);
    }
    __syncthreads();
    float* p = part + (size_t)blockIdx.x * (2 * BSZ);
    for (int j = threadIdx.x; j < BSZ; j += ABLK) {
        p[j] = a0[j];
        p[BSZ + j] = a1[j];
    }
}

__global__ void r2_kernel(const float* __restrict__ part, const float* __restrict__ dinv,
                          const float* __restrict__ os0, const float* __restrict__ os1,
                          const float* __restrict__ b2v, float2* __restrict__ out, int N) {
    int i = blockIdx.x * blockDim.x + threadIdx.x;
    if (i >= N) return;
    int b = i >> BSHIFT, dl = i & (BSZ - 1);
    float S0 = 0.0f, S1 = 0.0f;
    const float* p = part + (size_t)(b * R2REP) * (2 * BSZ) + dl;
#pragma unroll 4
    for (int r = 0; r < R2REP; ++r) {
        S0 += p[(size_t)r * (2 * BSZ)];
        S1 += p[(size_t)r * (2 * BSZ) + BSZ];
    }
    float di = dinv[i];
    float z0 = di * S0 + os0[i] + b2v[0];
    float z1 = di * S1 + os1[i] + b2v[1];
    float m = fmaxf(z0, z1), mn = fminf(z0, z1);
    float l = m + logf(1.0f + __expf(mn - m));
    out[i] = make_float2(z0 - l, z1 - l);
}

// ---------------- fallback (round-2 verified) ----------------

__global__ void deg_kernel(const int* __restrict__ dst, float* __restrict__ deg, int E) {
    int e = blockIdx.x * blockDim.x + threadIdx.x;
    if (e < E) atomicAdd(&deg[dst[e]], 1.0f);
}

__global__ void dinv_kernel(const float* __restrict__ deg, const float* __restrict__ x,
                            float* __restrict__ dinv, float* __restrict__ s1, int N) {
    int i = blockIdx.x * blockDim.x + threadIdx.x;
    if (i < N) {
        float di = rsqrtf(deg[i] + 1.0f);
        dinv[i] = di;
        s1[i] = di * di * x[i];
    }
}

__global__ void agg1_kernel(const int* __restrict__ src, const int* __restrict__ dst,
                            const float* __restrict__ x, const float* __restrict__ dinv,
                            float* __restrict__ s1, int E) {
    int e = blockIdx.x * blockDim.x + threadIdx.x;
    if (e < E) {
        int s = src[e], d = dst[e];
        atomicAdd(&s1[d], dinv[s] * dinv[d] * x[s]);
    }
}

__global__ void node_mlp_kernel(const float* __restrict__ s1, const float* __restrict__ dinv,
                                const float* __restrict__ W1, const float* __restrict__ b1,
                                const float* __restrict__ W2,
                                float* __restrict__ t0, float* __restrict__ t1,
                                float* __restrict__ o0, float* __restrict__ o1, int N) {
    __shared__ float sW1[32], sb1[32], sW2[64];
    int t = threadIdx.x;
    if (t < 32) { sW1[t] = W1[t]; sb1[t] = b1[t]; }
    if (t < 64) sW2[t] = W2[t];
    __syncthreads();
    int i = blockIdx.x * blockDim.x + t;
    if (i < N) {
        float s = s1[i];
        float a0 = 0.0f, a1 = 0.0f;
#pragma unroll
        for (int j = 0; j < 32; ++j) {
            float h = fmaxf(fmaf(s, sW1[j], sb1[j]), 0.0f);
            a0 = fmaf(h, sW2[2 * j], a0);
            a1 = fmaf(h, sW2[2 * j + 1], a1);
        }
        t0[i] = a0; t1[i] = a1;
        float d2 = dinv[i] * dinv[i];
        o0[i] = d2 * a0; o1[i] = d2 * a1;
    }
}

__global__ void agg2_kernel(const int* __restrict__ src, const int* __restrict__ dst,
                            const float* __restrict__ dinv,
                            const float* __restrict__ t0, const float* __restrict__ t1,
                            float* __restrict__ o0, float* __restrict__ o1, int E) {
    int e = blockIdx.x * blockDim.x + threadIdx.x;
    if (e < E) {
        int s = src[e], d = dst[e];
        float w = dinv[s] * dinv[d];
        atomicAdd(&o0[d], w * t0[s]);
        atomicAdd(&o1[d], w * t1[s]);
    }
}

__global__ void logsoftmax_kernel(const float* __restrict__ o0, const float* __restrict__ o1,
                                  const float* __restrict__ b2, float* __restrict__ out, int N) {
    int i = blockIdx.x * blockDim.x + threadIdx.x;
    if (i < N) {
        float z0 = o0[i] + b2[0];
        float z1 = o1[i] + b2[1];
        float m = fmaxf(z0, z1), mn = fminf(z0, z1);
        float l = m + logf(1.0f + __expf(mn - m));
        ((float2*)out)[i] = make_float2(z0 - l, z1 - l);
    }
}

// ---------------- launch ----------------

extern "C" void kernel_launch(void* const* d_in, const int* in_sizes, int n_in,
                              void* d_out, int out_size, void* d_ws, size_t ws_size,
                              hipStream_t stream) {
    const float* x  = (const float*)d_in[0];
    const int* ei   = (const int*)d_in[1];     // int32 (JAX x64 disabled)
    const float* W1 = (const float*)d_in[2];
    const float* b1 = (const float*)d_in[3];
    const float* W2 = (const float*)d_in[4];
    const float* b2 = (const float*)d_in[5];
    float* out = (float*)d_out;

    const int N = in_sizes[0];
    const int E = in_sizes[1] / 2;
    const int* src = ei;
    const int* dst = ei + E;

    // fast-path ws layout (bytes)
    const size_t OFF_CUR  = 0;                                    // 64 u32
    const size_t OFF_EBUF = 256;
    const size_t SZ_EBUF  = (size_t)NBK * CAP * 4;                // 28.1 MB
    const size_t OFF_PART = OFF_EBUF + SZ_EBUF;
    const size_t SZ_PART  = (size_t)NBK * R1REP * BSZ * 4;        // == NBK*R2REP*2*BSZ*4
    const size_t OFF_NODE = OFF_PART + SZ_PART;
    const size_t SZ_NODE  = (size_t)N * 4;
    const size_t NEED = OFF_NODE + 6 * SZ_NODE + 256;

    bool fast = (ws_size >= NEED) && (N <= NBK * BSZ) && (N < (1 << 17)) &&
                ((size_t)E * BSZ / (size_t)(N > 0 ? N : 1) + 20000 < CAP);

    if (fast) {
        unsigned* cursors = (unsigned*)((char*)d_ws + OFF_CUR);
        unsigned* ebuf    = (unsigned*)((char*)d_ws + OFF_EBUF);
        float*    part    = (float*)((char*)d_ws + OFF_PART);
        float*    dinv    = (float*)((char*)d_ws + OFF_NODE);
        float*    xd      = dinv + N;
        float*    os0     = xd + N;
        float*    os1     = os0 + N;
        float2*   ttp     = (float2*)(os1 + N);                   // 2N floats

        hipMemsetAsync(cursors, 0, 256, stream);

        int ablocks = (E + ACHUNK - 1) / ACHUNK;
        int ng = (N + 255) / 256;

        bucketize_kernel<<<ablocks, ABLK, 0, stream>>>(src, dst, cursors, ebuf, E);
        b0_deg_kernel<<<NBK * R1REP, ABLK, 0, stream>>>(ebuf, cursors, (unsigned*)part);
        r0_kernel<<<ng, 256, 0, stream>>>((unsigned*)part, x, dinv, xd, N);
        b1_agg1_kernel<<<NBK * R1REP, ABLK, 0, stream>>>(ebuf, cursors, xd, part);
        r1_kernel<<<ng, 256, 0, stream>>>(part, x, dinv, W1, b1, W2, ttp, os0, os1, N);
        b2_agg2_kernel<<<NBK * R2REP, ABLK, 0, stream>>>(ebuf, cursors, ttp, part);
        r2_kernel<<<ng, 256, 0, stream>>>(part, dinv, os0, os1, b2, (float2*)out, N);
    } else {
        float* deg  = (float*)d_ws;
        float* dinv = deg + N;
        float* s1   = dinv + N;
        float* t0   = s1 + N;
        float* t1   = t0 + N;
        float* o0   = t1 + N;
        float* o1   = o0 + N;

        hipMemsetAsync(deg, 0, (size_t)N * sizeof(float), stream);
        int eg = (E + 255) / 256, ng = (N + 255) / 256;
        deg_kernel<<<eg, 256, 0, stream>>>(dst, deg, E);
        dinv_kernel<<<ng, 256, 0, stream>>>(deg, x, dinv, s1, N);
        agg1_kernel<<<eg, 256, 0, stream>>>(src, dst, x, dinv, s1, E);
        node_mlp_kernel<<<ng, 256, 0, stream>>>(s1, dinv, W1, b1, W2, t0, t1, o0, o1, N);
        agg2_kernel<<<eg, 256, 0, stream>>>(src, dst, dinv, t0, t1, o0, o1, E);
        logsoftmax_kernel<<<ng, 256, 0, stream>>>(o0, o1, b2, out, N);
    }
}

// Round 4
// 269.150 us; speedup vs baseline: 5.1121x; 5.1118x over previous
//
#include <hip/hip_runtime.h>
#include <math.h>

// GCN 2-layer, MI355X. Round 4: R3's bucketed-LDS fast path never engaged —
// guard demanded +20000 margin vs CAP's +16384 (524288+20000 > 540672). Fix
// the guard; design otherwise identical. Nodes in NBK buckets of BSZ=8192
// (32KB LDS accumulator); edges packed once as u32 (src<<13 | dst_local);
// each agg pass = sequential edge read + LDS atomics + coalesced partial
// writes + tree reduce. Global atomics only for bucketize cursors (~10k).

#define NBK     13
#define BSHIFT  13
#define BSZ     8192            // nodes per bucket
#define CAP     540672          // per-bucket edge capacity = 524288 + 16384 (23 sigma)
#define R1REP   40              // replicas/bucket for deg & agg1 (grid 520)
#define R2REP   20              // replicas/bucket for agg2 (grid 260)
#define ABLK    512             // threads for bucket/agg kernels
#define ACHUNK  8192            // edges per bucketize block (16/thread)

// ---------------- fast path kernels ----------------

__global__ void bucketize_kernel(const int* __restrict__ src, const int* __restrict__ dst,
                                 unsigned* __restrict__ cursors, unsigned* __restrict__ ebuf,
                                 int E) {
    __shared__ unsigned cnt[NBK], base[NBK], run[NBK];
    int t = threadIdx.x;
    if (t < NBK) cnt[t] = 0;
    __syncthreads();
    int e0 = blockIdx.x * ACHUNK;
    int dd[16], ss[16];
#pragma unroll
    for (int k = 0; k < 16; ++k) {
        int e = e0 + k * ABLK + t;
        if (e < E) {
            dd[k] = dst[e];
            ss[k] = src[e];
            atomicAdd(&cnt[dd[k] >> BSHIFT], 1u);
        } else dd[k] = -1;
    }
    __syncthreads();
    if (t < NBK) { base[t] = atomicAdd(&cursors[t], cnt[t]); run[t] = 0; }
    __syncthreads();
#pragma unroll
    for (int k = 0; k < 16; ++k) {
        if (dd[k] >= 0) {
            int b = dd[k] >> BSHIFT;
            unsigned pos = base[b] + atomicAdd(&run[b], 1u);
            if (pos < (unsigned)CAP)
                ebuf[(size_t)b * CAP + pos] =
                    ((unsigned)ss[k] << BSHIFT) | (unsigned)(dd[k] & (BSZ - 1));
        }
    }
}

__global__ void b0_deg_kernel(const unsigned* __restrict__ ebuf,
                              const unsigned* __restrict__ cursors,
                              unsigned* __restrict__ part) {
    __shared__ unsigned acc[BSZ];
    int b = blockIdx.x / R1REP, r = blockIdx.x % R1REP;
    for (int j = threadIdx.x; j < BSZ; j += ABLK) acc[j] = 0;
    __syncthreads();
    unsigned c = cursors[b]; if (c > (unsigned)CAP) c = CAP;
    unsigned per = (c + R1REP - 1) / R1REP;
    unsigned i0 = r * per, i1 = i0 + per; if (i1 > c) i1 = c;
    const unsigned* eb = ebuf + (size_t)b * CAP;
    for (unsigned i = i0 + threadIdx.x; i < i1; i += ABLK)
        atomicAdd(&acc[eb[i] & (BSZ - 1)], 1u);
    __syncthreads();
    unsigned* p = part + (size_t)blockIdx.x * BSZ;
    for (int j = threadIdx.x; j < BSZ; j += ABLK) p[j] = acc[j];
}

__global__ void r0_kernel(const unsigned* __restrict__ part, const float* __restrict__ x,
                          float* __restrict__ dinv, float* __restrict__ xd, int N) {
    int i = blockIdx.x * blockDim.x + threadIdx.x;
    if (i >= N) return;
    int b = i >> BSHIFT, dl = i & (BSZ - 1);
    unsigned deg = 0;
    const unsigned* p = part + (size_t)(b * R1REP) * BSZ + dl;
#pragma unroll 4
    for (int r = 0; r < R1REP; ++r) deg += p[(size_t)r * BSZ];
    float di = rsqrtf((float)deg + 1.0f);
    dinv[i] = di;
    xd[i] = di * x[i];
}

__global__ void b1_agg1_kernel(const unsigned* __restrict__ ebuf,
                               const unsigned* __restrict__ cursors,
                               const float* __restrict__ xd,
                               float* __restrict__ part) {
    __shared__ float acc[BSZ];
    int b = blockIdx.x / R1REP, r = blockIdx.x % R1REP;
    for (int j = threadIdx.x; j < BSZ; j += ABLK) acc[j] = 0.0f;
    __syncthreads();
    unsigned c = cursors[b]; if (c > (unsigned)CAP) c = CAP;
    unsigned per = (c + R1REP - 1) / R1REP;
    unsigned i0 = r * per, i1 = i0 + per; if (i1 > c) i1 = c;
    const unsigned* eb = ebuf + (size_t)b * CAP;
    for (unsigned i = i0 + threadIdx.x; i < i1; i += ABLK) {
        unsigned pk = eb[i];
        atomicAdd(&acc[pk & (BSZ - 1)], xd[pk >> BSHIFT]);
    }
    __syncthreads();
    float* p = (float*)part + (size_t)blockIdx.x * BSZ;
    for (int j = threadIdx.x; j < BSZ; j += ABLK) p[j] = acc[j];
}

__global__ void r1_kernel(const float* __restrict__ part, const float* __restrict__ x,
                          const float* __restrict__ dinv,
                          const float* __restrict__ W1, const float* __restrict__ b1,
                          const float* __restrict__ W2,
                          float2* __restrict__ ttp, float* __restrict__ os0,
                          float* __restrict__ os1, int N) {
    __shared__ float sW1[32], sb1[32], sW2[64];
    int t = threadIdx.x;
    if (t < 32) { sW1[t] = W1[t]; sb1[t] = b1[t]; }
    if (t < 64) sW2[t] = W2[t];
    __syncthreads();
    int i = blockIdx.x * blockDim.x + t;
    if (i >= N) return;
    int b = i >> BSHIFT, dl = i & (BSZ - 1);
    float S = 0.0f;
    const float* p = part + (size_t)(b * R1REP) * BSZ + dl;
#pragma unroll 4
    for (int r = 0; r < R1REP; ++r) S += p[(size_t)r * BSZ];
    float di = dinv[i];
    float s1v = di * di * x[i] + di * S;
    float a0 = 0.0f, a1 = 0.0f;
#pragma unroll
    for (int j = 0; j < 32; ++j) {
        float h = fmaxf(fmaf(s1v, sW1[j], sb1[j]), 0.0f);
        a0 = fmaf(h, sW2[2 * j], a0);
        a1 = fmaf(h, sW2[2 * j + 1], a1);
    }
    ttp[i] = make_float2(di * a0, di * a1);
    os0[i] = di * di * a0;
    os1[i] = di * di * a1;
}

__global__ void b2_agg2_kernel(const unsigned* __restrict__ ebuf,
                               const unsigned* __restrict__ cursors,
                               const float2* __restrict__ ttp,
                               float* __restrict__ part) {
    __shared__ float a0[BSZ];
    __shared__ float a1[BSZ];
    int b = blockIdx.x / R2REP, r = blockIdx.x % R2REP;
    for (int j = threadIdx.x; j < BSZ; j += ABLK) { a0[j] = 0.0f; a1[j] = 0.0f; }
    __syncthreads();
    unsigned c = cursors[b]; if (c > (unsigned)CAP) c = CAP;
    unsigned per = (c + R2REP - 1) / R2REP;
    unsigned i0 = r * per, i1 = i0 + per; if (i1 > c) i1 = c;
    const unsigned* eb = ebuf + (size_t)b * CAP;
    for (unsigned i = i0 + threadIdx.x; i < i1; i += ABLK) {
        unsigned pk = eb[i];
        int dl = pk & (BSZ - 1);
        float2 v = ttp[pk >> BSHIFT];
        atomicAdd(&a0[dl], v.x);
        atomicAdd(&a1[dl], v.y);
    }
    __syncthreads();
    float* p = part + (size_t)blockIdx.x * (2 * BSZ);
    for (int j = threadIdx.x; j < BSZ; j += ABLK) {
        p[j] = a0[j];
        p[BSZ + j] = a1[j];
    }
}

__global__ void r2_kernel(const float* __restrict__ part, const float* __restrict__ dinv,
                          const float* __restrict__ os0, const float* __restrict__ os1,
                          const float* __restrict__ b2v, float2* __restrict__ out, int N) {
    int i = blockIdx.x * blockDim.x + threadIdx.x;
    if (i >= N) return;
    int b = i >> BSHIFT, dl = i & (BSZ - 1);
    float S0 = 0.0f, S1 = 0.0f;
    const float* p = part + (size_t)(b * R2REP) * (2 * BSZ) + dl;
#pragma unroll 4
    for (int r = 0; r < R2REP; ++r) {
        S0 += p[(size_t)r * (2 * BSZ)];
        S1 += p[(size_t)r * (2 * BSZ) + BSZ];
    }
    float di = dinv[i];
    float z0 = di * S0 + os0[i] + b2v[0];
    float z1 = di * S1 + os1[i] + b2v[1];
    float m = fmaxf(z0, z1), mn = fminf(z0, z1);
    float l = m + logf(1.0f + __expf(mn - m));
    out[i] = make_float2(z0 - l, z1 - l);
}

// ---------------- fallback (round-2 verified) ----------------

__global__ void deg_kernel(const int* __restrict__ dst, float* __restrict__ deg, int E) {
    int e = blockIdx.x * blockDim.x + threadIdx.x;
    if (e < E) atomicAdd(&deg[dst[e]], 1.0f);
}

__global__ void dinv_kernel(const float* __restrict__ deg, const float* __restrict__ x,
                            float* __restrict__ dinv, float* __restrict__ s1, int N) {
    int i = blockIdx.x * blockDim.x + threadIdx.x;
    if (i < N) {
        float di = rsqrtf(deg[i] + 1.0f);
        dinv[i] = di;
        s1[i] = di * di * x[i];
    }
}

__global__ void agg1_kernel(const int* __restrict__ src, const int* __restrict__ dst,
                            const float* __restrict__ x, const float* __restrict__ dinv,
                            float* __restrict__ s1, int E) {
    int e = blockIdx.x * blockDim.x + threadIdx.x;
    if (e < E) {
        int s = src[e], d = dst[e];
        atomicAdd(&s1[d], dinv[s] * dinv[d] * x[s]);
    }
}

__global__ void node_mlp_kernel(const float* __restrict__ s1, const float* __restrict__ dinv,
                                const float* __restrict__ W1, const float* __restrict__ b1,
                                const float* __restrict__ W2,
                                float* __restrict__ t0, float* __restrict__ t1,
                                float* __restrict__ o0, float* __restrict__ o1, int N) {
    __shared__ float sW1[32], sb1[32], sW2[64];
    int t = threadIdx.x;
    if (t < 32) { sW1[t] = W1[t]; sb1[t] = b1[t]; }
    if (t < 64) sW2[t] = W2[t];
    __syncthreads();
    int i = blockIdx.x * blockDim.x + t;
    if (i < N) {
        float s = s1[i];
        float a0 = 0.0f, a1 = 0.0f;
#pragma unroll
        for (int j = 0; j < 32; ++j) {
            float h = fmaxf(fmaf(s, sW1[j], sb1[j]), 0.0f);
            a0 = fmaf(h, sW2[2 * j], a0);
            a1 = fmaf(h, sW2[2 * j + 1], a1);
        }
        t0[i] = a0; t1[i] = a1;
        float d2 = dinv[i] * dinv[i];
        o0[i] = d2 * a0; o1[i] = d2 * a1;
    }
}

__global__ void agg2_kernel(const int* __restrict__ src, const int* __restrict__ dst,
                            const float* __restrict__ dinv,
                            const float* __restrict__ t0, const float* __restrict__ t1,
                            float* __restrict__ o0, float* __restrict__ o1, int E) {
    int e = blockIdx.x * blockDim.x + threadIdx.x;
    if (e < E) {
        int s = src[e], d = dst[e];
        float w = dinv[s] * dinv[d];
        atomicAdd(&o0[d], w * t0[s]);
        atomicAdd(&o1[d], w * t1[s]);
    }
}

__global__ void logsoftmax_kernel(const float* __restrict__ o0, const float* __restrict__ o1,
                                  const float* __restrict__ b2, float* __restrict__ out, int N) {
    int i = blockIdx.x * blockDim.x + threadIdx.x;
    if (i < N) {
        float z0 = o0[i] + b2[0];
        float z1 = o1[i] + b2[1];
        float m = fmaxf(z0, z1), mn = fminf(z0, z1);
        float l = m + logf(1.0f + __expf(mn - m));
        ((float2*)out)[i] = make_float2(z0 - l, z1 - l);
    }
}

// ---------------- launch ----------------

extern "C" void kernel_launch(void* const* d_in, const int* in_sizes, int n_in,
                              void* d_out, int out_size, void* d_ws, size_t ws_size,
                              hipStream_t stream) {
    const float* x  = (const float*)d_in[0];
    const int* ei   = (const int*)d_in[1];     // int32 (JAX x64 disabled)
    const float* W1 = (const float*)d_in[2];
    const float* b1 = (const float*)d_in[3];
    const float* W2 = (const float*)d_in[4];
    const float* b2 = (const float*)d_in[5];
    float* out = (float*)d_out;

    const int N = in_sizes[0];
    const int E = in_sizes[1] / 2;
    const int* src = ei;
    const int* dst = ei + E;

    // fast-path ws layout (bytes)
    const size_t OFF_CUR  = 0;                                    // 64 u32
    const size_t OFF_EBUF = 256;
    const size_t SZ_EBUF  = (size_t)NBK * CAP * 4;                // 28.1 MB
    const size_t OFF_PART = OFF_EBUF + SZ_EBUF;
    const size_t SZ_PART  = (size_t)NBK * R1REP * BSZ * 4;        // == NBK*R2REP*2*BSZ*4
    const size_t OFF_NODE = OFF_PART + SZ_PART;
    const size_t SZ_NODE  = (size_t)N * 4;
    const size_t NEED = OFF_NODE + 6 * SZ_NODE + 256;

    // Guard matches CAP's actual margin: expected E*BSZ/N + 16384 (23 sigma) <= CAP.
    bool fast = (ws_size >= NEED) && (N <= NBK * BSZ) && (N < (1 << 17)) && N > 0 &&
                ((size_t)E * BSZ / (size_t)N + 16384 <= (size_t)CAP);

    if (fast) {
        unsigned* cursors = (unsigned*)((char*)d_ws + OFF_CUR);
        unsigned* ebuf    = (unsigned*)((char*)d_ws + OFF_EBUF);
        float*    part    = (float*)((char*)d_ws + OFF_PART);
        float*    dinv    = (float*)((char*)d_ws + OFF_NODE);
        float*    xd      = dinv + N;
        float*    os0     = xd + N;
        float*    os1     = os0 + N;
        float2*   ttp     = (float2*)(os1 + N);                   // 2N floats

        hipMemsetAsync(cursors, 0, 256, stream);

        int ablocks = (E + ACHUNK - 1) / ACHUNK;
        int ng = (N + 255) / 256;

        bucketize_kernel<<<ablocks, ABLK, 0, stream>>>(src, dst, cursors, ebuf, E);
        b0_deg_kernel<<<NBK * R1REP, ABLK, 0, stream>>>(ebuf, cursors, (unsigned*)part);
        r0_kernel<<<ng, 256, 0, stream>>>((unsigned*)part, x, dinv, xd, N);
        b1_agg1_kernel<<<NBK * R1REP, ABLK, 0, stream>>>(ebuf, cursors, xd, part);
        r1_kernel<<<ng, 256, 0, stream>>>(part, x, dinv, W1, b1, W2, ttp, os0, os1, N);
        b2_agg2_kernel<<<NBK * R2REP, ABLK, 0, stream>>>(ebuf, cursors, ttp, part);
        r2_kernel<<<ng, 256, 0, stream>>>(part, dinv, os0, os1, b2, (float2*)out, N);
    } else {
        float* deg  = (float*)d_ws;
        float* dinv = deg + N;
        float* s1   = dinv + N;
        float* t0   = s1 + N;
        float* t1   = t0 + N;
        float* o0   = t1 + N;
        float* o1   = o0 + N;

        hipMemsetAsync(deg, 0, (size_t)N * sizeof(float), stream);
        int eg = (E + 255) / 256, ng = (N + 255) / 256;
        deg_kernel<<<eg, 256, 0, stream>>>(dst, deg, E);
        dinv_kernel<<<ng, 256, 0, stream>>>(deg, x, dinv, s1, N);
        agg1_kernel<<<eg, 256, 0, stream>>>(src, dst, x, dinv, s1, E);
        node_mlp_kernel<<<ng, 256, 0, stream>>>(s1, dinv, W1, b1, W2, t0, t1, o0, o1, N);
        agg2_kernel<<<eg, 256, 0, stream>>>(src, dst, dinv, t0, t1, o0, o1, E);
        logsoftmax_kernel<<<ng, 256, 0, stream>>>(o0, o1, b2, out, N);
    }
}

// Round 5
// 255.627 us; speedup vs baseline: 5.3825x; 1.0529x over previous
//
#include <hip/hip_runtime.h>
#include <math.h>

// GCN 2-layer, MI355X. Round 5: R4's agg kernels were latency-bound
// (b2: occupancy 18%, VALUBusy 1.8%, HBM 4.7% -- serial edge->gather->LDS
// chain, 1 block/CU). Fix: 1024-thread agg blocks (2x waves/CU), uint4 edge
// loads (4 gathers in flight), LDS-staged coalesced bucketize writes.
// ws layout identical to R4 (proven to fit).

#define NBK     13
#define BSHIFT  13
#define BSZ     8192            // nodes per bucket
#define CAP     540672          // per-bucket edge capacity = 524288 + 16384 (23 sigma)
#define R1REP   40              // replicas/bucket for deg & agg1 (grid 520)
#define R2REP   20              // replicas/bucket for agg2 (grid 260)
#define ABLK    1024            // threads for agg kernels
#define BBLK    512             // threads for bucketize
#define ACHUNK  8192            // edges per bucketize block (16/thread)

// ---------------- fast path kernels ----------------

__global__ __launch_bounds__(BBLK) void bucketize_kernel(
        const int* __restrict__ src, const int* __restrict__ dst,
        unsigned* __restrict__ cursors, unsigned* __restrict__ ebuf, int E) {
    __shared__ unsigned stage[ACHUNK];          // 32 KB
    __shared__ unsigned cnt[NBK], gbase[NBK], loff[NBK], run[NBK];
    int t = threadIdx.x;
    if (t < NBK) { cnt[t] = 0; run[t] = 0; }
    __syncthreads();
    int e0 = blockIdx.x * ACHUNK;
    unsigned pk[16];
    int bb[16];
#pragma unroll
    for (int k = 0; k < 4; ++k) {
        int be = e0 + k * (BBLK * 4) + t * 4;
        if (be + 4 <= E) {
            int4 s4 = *(const int4*)(src + be);
            int4 d4 = *(const int4*)(dst + be);
            pk[k*4+0] = ((unsigned)s4.x << BSHIFT) | ((unsigned)d4.x & (BSZ-1)); bb[k*4+0] = d4.x >> BSHIFT;
            pk[k*4+1] = ((unsigned)s4.y << BSHIFT) | ((unsigned)d4.y & (BSZ-1)); bb[k*4+1] = d4.y >> BSHIFT;
            pk[k*4+2] = ((unsigned)s4.z << BSHIFT) | ((unsigned)d4.z & (BSZ-1)); bb[k*4+2] = d4.z >> BSHIFT;
            pk[k*4+3] = ((unsigned)s4.w << BSHIFT) | ((unsigned)d4.w & (BSZ-1)); bb[k*4+3] = d4.w >> BSHIFT;
            atomicAdd(&cnt[bb[k*4+0]], 1u);
            atomicAdd(&cnt[bb[k*4+1]], 1u);
            atomicAdd(&cnt[bb[k*4+2]], 1u);
            atomicAdd(&cnt[bb[k*4+3]], 1u);
        } else {
#pragma unroll
            for (int j = 0; j < 4; ++j) {
                int e = be + j;
                if (e < E) {
                    int s = src[e], d = dst[e];
                    pk[k*4+j] = ((unsigned)s << BSHIFT) | ((unsigned)d & (BSZ-1));
                    bb[k*4+j] = d >> BSHIFT;
                    atomicAdd(&cnt[bb[k*4+j]], 1u);
                } else bb[k*4+j] = -1;
            }
        }
    }
    __syncthreads();
    if (t == 0) {
        unsigned acc = 0;
        for (int b = 0; b < NBK; ++b) { loff[b] = acc; acc += cnt[b]; }
    }
    __syncthreads();
    if (t < NBK && cnt[t] > 0) gbase[t] = atomicAdd(&cursors[t], cnt[t]);
#pragma unroll
    for (int k = 0; k < 16; ++k) {
        if (bb[k] >= 0) {
            unsigned p = loff[bb[k]] + atomicAdd(&run[bb[k]], 1u);
            stage[p] = pk[k];
        }
    }
    __syncthreads();
    for (int b = 0; b < NBK; ++b) {
        unsigned n = cnt[b], lo = loff[b], go = gbase[b];
        unsigned* dp = ebuf + (size_t)b * CAP;
        for (unsigned j = t; j < n; j += BBLK) {
            unsigned pos = go + j;
            if (pos < (unsigned)CAP) dp[pos] = stage[lo + j];
        }
    }
}

__global__ __launch_bounds__(ABLK) void b0_deg_kernel(
        const unsigned* __restrict__ ebuf, const unsigned* __restrict__ cursors,
        unsigned* __restrict__ part) {
    __shared__ unsigned acc[BSZ];               // 32 KB
    int b = blockIdx.x / R1REP, r = blockIdx.x % R1REP;
    for (int j = threadIdx.x; j < BSZ; j += ABLK) acc[j] = 0;
    __syncthreads();
    unsigned c = cursors[b]; if (c > (unsigned)CAP) c = CAP;
    unsigned per = (((c + R1REP - 1) / R1REP) + 3u) & ~3u;
    unsigned i0 = r * per, i1 = i0 + per; if (i1 > c) i1 = c;
    const unsigned* eb = ebuf + (size_t)b * CAP;
    unsigned base = i0 + threadIdx.x * 4;
    for (; base + 4 <= i1; base += ABLK * 4) {
        uint4 pk = *(const uint4*)(eb + base);
        atomicAdd(&acc[pk.x & (BSZ-1)], 1u);
        atomicAdd(&acc[pk.y & (BSZ-1)], 1u);
        atomicAdd(&acc[pk.z & (BSZ-1)], 1u);
        atomicAdd(&acc[pk.w & (BSZ-1)], 1u);
    }
    if (base < i1) {
        for (unsigned i = base; i < i1; ++i) atomicAdd(&acc[eb[i] & (BSZ-1)], 1u);
    }
    __syncthreads();
    unsigned* p = part + (size_t)blockIdx.x * BSZ;
    for (int j = threadIdx.x; j < BSZ; j += ABLK) p[j] = acc[j];
}

__global__ void r0_kernel(const unsigned* __restrict__ part, const float* __restrict__ x,
                          float* __restrict__ dinv, float* __restrict__ xd, int N) {
    int i = blockIdx.x * blockDim.x + threadIdx.x;
    if (i >= N) return;
    int b = i >> BSHIFT, dl = i & (BSZ - 1);
    unsigned deg = 0;
    const unsigned* p = part + (size_t)(b * R1REP) * BSZ + dl;
#pragma unroll 8
    for (int r = 0; r < R1REP; ++r) deg += p[(size_t)r * BSZ];
    float di = rsqrtf((float)deg + 1.0f);
    dinv[i] = di;
    xd[i] = di * x[i];
}

__global__ __launch_bounds__(ABLK) void b1_agg1_kernel(
        const unsigned* __restrict__ ebuf, const unsigned* __restrict__ cursors,
        const float* __restrict__ xd, float* __restrict__ part) {
    __shared__ float acc[BSZ];                  // 32 KB
    int b = blockIdx.x / R1REP, r = blockIdx.x % R1REP;
    for (int j = threadIdx.x; j < BSZ; j += ABLK) acc[j] = 0.0f;
    __syncthreads();
    unsigned c = cursors[b]; if (c > (unsigned)CAP) c = CAP;
    unsigned per = (((c + R1REP - 1) / R1REP) + 3u) & ~3u;
    unsigned i0 = r * per, i1 = i0 + per; if (i1 > c) i1 = c;
    const unsigned* eb = ebuf + (size_t)b * CAP;
    unsigned base = i0 + threadIdx.x * 4;
    for (; base + 4 <= i1; base += ABLK * 4) {
        uint4 pk = *(const uint4*)(eb + base);
        float v0 = xd[pk.x >> BSHIFT];
        float v1 = xd[pk.y >> BSHIFT];
        float v2 = xd[pk.z >> BSHIFT];
        float v3 = xd[pk.w >> BSHIFT];
        atomicAdd(&acc[pk.x & (BSZ-1)], v0);
        atomicAdd(&acc[pk.y & (BSZ-1)], v1);
        atomicAdd(&acc[pk.z & (BSZ-1)], v2);
        atomicAdd(&acc[pk.w & (BSZ-1)], v3);
    }
    if (base < i1) {
        for (unsigned i = base; i < i1; ++i) {
            unsigned pk = eb[i];
            atomicAdd(&acc[pk & (BSZ-1)], xd[pk >> BSHIFT]);
        }
    }
    __syncthreads();
    float* p = part + (size_t)blockIdx.x * BSZ;
    for (int j = threadIdx.x; j < BSZ; j += ABLK) p[j] = acc[j];
}

__global__ void r1_kernel(const float* __restrict__ part, const float* __restrict__ x,
                          const float* __restrict__ dinv,
                          const float* __restrict__ W1, const float* __restrict__ b1,
                          const float* __restrict__ W2,
                          float2* __restrict__ ttp, float* __restrict__ os0,
                          float* __restrict__ os1, int N) {
    __shared__ float sW1[32], sb1[32], sW2[64];
    int t = threadIdx.x;
    if (t < 32) { sW1[t] = W1[t]; sb1[t] = b1[t]; }
    if (t < 64) sW2[t] = W2[t];
    __syncthreads();
    int i = blockIdx.x * blockDim.x + t;
    if (i >= N) return;
    int b = i >> BSHIFT, dl = i & (BSZ - 1);
    float S = 0.0f;
    const float* p = part + (size_t)(b * R1REP) * BSZ + dl;
#pragma unroll 8
    for (int r = 0; r < R1REP; ++r) S += p[(size_t)r * BSZ];
    float di = dinv[i];
    float s1v = di * di * x[i] + di * S;
    float a0 = 0.0f, a1 = 0.0f;
#pragma unroll
    for (int j = 0; j < 32; ++j) {
        float h = fmaxf(fmaf(s1v, sW1[j], sb1[j]), 0.0f);
        a0 = fmaf(h, sW2[2 * j], a0);
        a1 = fmaf(h, sW2[2 * j + 1], a1);
    }
    ttp[i] = make_float2(di * a0, di * a1);
    os0[i] = di * di * a0;
    os1[i] = di * di * a1;
}

__global__ __launch_bounds__(ABLK) void b2_agg2_kernel(
        const unsigned* __restrict__ ebuf, const unsigned* __restrict__ cursors,
        const float2* __restrict__ ttp, float* __restrict__ part) {
    __shared__ float a0[BSZ];                   // 32 KB
    __shared__ float a1[BSZ];                   // 32 KB
    int b = blockIdx.x / R2REP, r = blockIdx.x % R2REP;
    for (int j = threadIdx.x; j < BSZ; j += ABLK) { a0[j] = 0.0f; a1[j] = 0.0f; }
    __syncthreads();
    unsigned c = cursors[b]; if (c > (unsigned)CAP) c = CAP;
    unsigned per = (((c + R2REP - 1) / R2REP) + 3u) & ~3u;
    unsigned i0 = r * per, i1 = i0 + per; if (i1 > c) i1 = c;
    const unsigned* eb = ebuf + (size_t)b * CAP;
    unsigned base = i0 + threadIdx.x * 4;
    for (; base + 4 <= i1; base += ABLK * 4) {
        uint4 pk = *(const uint4*)(eb + base);
        float2 v0 = ttp[pk.x >> BSHIFT];
        float2 v1 = ttp[pk.y >> BSHIFT];
        float2 v2 = ttp[pk.z >> BSHIFT];
        float2 v3 = ttp[pk.w >> BSHIFT];
        atomicAdd(&a0[pk.x & (BSZ-1)], v0.x);
        atomicAdd(&a1[pk.x & (BSZ-1)], v0.y);
        atomicAdd(&a0[pk.y & (BSZ-1)], v1.x);
        atomicAdd(&a1[pk.y & (BSZ-1)], v1.y);
        atomicAdd(&a0[pk.z & (BSZ-1)], v2.x);
        atomicAdd(&a1[pk.z & (BSZ-1)], v2.y);
        atomicAdd(&a0[pk.w & (BSZ-1)], v3.x);
        atomicAdd(&a1[pk.w & (BSZ-1)], v3.y);
    }
    if (base < i1) {
        for (unsigned i = base; i < i1; ++i) {
            unsigned pk = eb[i];
            float2 v = ttp[pk >> BSHIFT];
            atomicAdd(&a0[pk & (BSZ-1)], v.x);
            atomicAdd(&a1[pk & (BSZ-1)], v.y);
        }
    }
    __syncthreads();
    float* p = part + (size_t)blockIdx.x * (2 * BSZ);
    for (int j = threadIdx.x; j < BSZ; j += ABLK) {
        p[j] = a0[j];
        p[BSZ + j] = a1[j];
    }
}

__global__ void r2_kernel(const float* __restrict__ part, const float* __restrict__ dinv,
                          const float* __restrict__ os0, const float* __restrict__ os1,
                          const float* __restrict__ b2v, float2* __restrict__ out, int N) {
    int i = blockIdx.x * blockDim.x + threadIdx.x;
    if (i >= N) return;
    int b = i >> BSHIFT, dl = i & (BSZ - 1);
    float S0 = 0.0f, S1 = 0.0f;
    const float* p = part + (size_t)(b * R2REP) * (2 * BSZ) + dl;
#pragma unroll 4
    for (int r = 0; r < R2REP; ++r) {
        S0 += p[(size_t)r * (2 * BSZ)];
        S1 += p[(size_t)r * (2 * BSZ) + BSZ];
    }
    float di = dinv[i];
    float z0 = di * S0 + os0[i] + b2v[0];
    float z1 = di * S1 + os1[i] + b2v[1];
    float m = fmaxf(z0, z1), mn = fminf(z0, z1);
    float l = m + logf(1.0f + __expf(mn - m));
    out[i] = make_float2(z0 - l, z1 - l);
}

// ---------------- fallback (round-2 verified) ----------------

__global__ void deg_kernel(const int* __restrict__ dst, float* __restrict__ deg, int E) {
    int e = blockIdx.x * blockDim.x + threadIdx.x;
    if (e < E) atomicAdd(&deg[dst[e]], 1.0f);
}

__global__ void dinv_kernel(const float* __restrict__ deg, const float* __restrict__ x,
                            float* __restrict__ dinv, float* __restrict__ s1, int N) {
    int i = blockIdx.x * blockDim.x + threadIdx.x;
    if (i < N) {
        float di = rsqrtf(deg[i] + 1.0f);
        dinv[i] = di;
        s1[i] = di * di * x[i];
    }
}

__global__ void agg1_kernel(const int* __restrict__ src, const int* __restrict__ dst,
                            const float* __restrict__ x, const float* __restrict__ dinv,
                            float* __restrict__ s1, int E) {
    int e = blockIdx.x * blockDim.x + threadIdx.x;
    if (e < E) {
        int s = src[e], d = dst[e];
        atomicAdd(&s1[d], dinv[s] * dinv[d] * x[s]);
    }
}

__global__ void node_mlp_kernel(const float* __restrict__ s1, const float* __restrict__ dinv,
                                const float* __restrict__ W1, const float* __restrict__ b1,
                                const float* __restrict__ W2,
                                float* __restrict__ t0, float* __restrict__ t1,
                                float* __restrict__ o0, float* __restrict__ o1, int N) {
    __shared__ float sW1[32], sb1[32], sW2[64];
    int t = threadIdx.x;
    if (t < 32) { sW1[t] = W1[t]; sb1[t] = b1[t]; }
    if (t < 64) sW2[t] = W2[t];
    __syncthreads();
    int i = blockIdx.x * blockDim.x + t;
    if (i < N) {
        float s = s1[i];
        float a0 = 0.0f, a1 = 0.0f;
#pragma unroll
        for (int j = 0; j < 32; ++j) {
            float h = fmaxf(fmaf(s, sW1[j], sb1[j]), 0.0f);
            a0 = fmaf(h, sW2[2 * j], a0);
            a1 = fmaf(h, sW2[2 * j + 1], a1);
        }
        t0[i] = a0; t1[i] = a1;
        float d2 = dinv[i] * dinv[i];
        o0[i] = d2 * a0; o1[i] = d2 * a1;
    }
}

__global__ void agg2_kernel(const int* __restrict__ src, const int* __restrict__ dst,
                            const float* __restrict__ dinv,
                            const float* __restrict__ t0, const float* __restrict__ t1,
                            float* __restrict__ o0, float* __restrict__ o1, int E) {
    int e = blockIdx.x * blockDim.x + threadIdx.x;
    if (e < E) {
        int s = src[e], d = dst[e];
        float w = dinv[s] * dinv[d];
        atomicAdd(&o0[d], w * t0[s]);
        atomicAdd(&o1[d], w * t1[s]);
    }
}

__global__ void logsoftmax_kernel(const float* __restrict__ o0, const float* __restrict__ o1,
                                  const float* __restrict__ b2, float* __restrict__ out, int N) {
    int i = blockIdx.x * blockDim.x + threadIdx.x;
    if (i < N) {
        float z0 = o0[i] + b2[0];
        float z1 = o1[i] + b2[1];
        float m = fmaxf(z0, z1), mn = fminf(z0, z1);
        float l = m + logf(1.0f + __expf(mn - m));
        ((float2*)out)[i] = make_float2(z0 - l, z1 - l);
    }
}

// ---------------- launch ----------------

extern "C" void kernel_launch(void* const* d_in, const int* in_sizes, int n_in,
                              void* d_out, int out_size, void* d_ws, size_t ws_size,
                              hipStream_t stream) {
    const float* x  = (const float*)d_in[0];
    const int* ei   = (const int*)d_in[1];     // int32 (JAX x64 disabled)
    const float* W1 = (const float*)d_in[2];
    const float* b1 = (const float*)d_in[3];
    const float* W2 = (const float*)d_in[4];
    const float* b2 = (const float*)d_in[5];
    float* out = (float*)d_out;

    const int N = in_sizes[0];
    const int E = in_sizes[1] / 2;
    const int* src = ei;
    const int* dst = ei + E;

    // fast-path ws layout (bytes) -- identical to R4 (proven fit)
    const size_t OFF_CUR  = 0;                                    // 64 u32
    const size_t OFF_EBUF = 256;
    const size_t SZ_EBUF  = (size_t)NBK * CAP * 4;                // 28.1 MB
    const size_t OFF_PART = OFF_EBUF + SZ_EBUF;
    const size_t SZ_PART  = (size_t)NBK * R1REP * BSZ * 4;        // == NBK*R2REP*2*BSZ*4
    const size_t OFF_NODE = OFF_PART + SZ_PART;
    const size_t SZ_NODE  = (size_t)N * 4;
    const size_t NEED = OFF_NODE + 6 * SZ_NODE + 256;

    bool fast = (ws_size >= NEED) && (N <= NBK * BSZ) && (N < (1 << 17)) && N > 0 &&
                ((size_t)E * BSZ / (size_t)N + 16384 <= (size_t)CAP);

    if (fast) {
        unsigned* cursors = (unsigned*)((char*)d_ws + OFF_CUR);
        unsigned* ebuf    = (unsigned*)((char*)d_ws + OFF_EBUF);
        float*    part    = (float*)((char*)d_ws + OFF_PART);
        float*    dinv    = (float*)((char*)d_ws + OFF_NODE);
        float*    xd      = dinv + N;
        float*    os0     = xd + N;
        float*    os1     = os0 + N;
        float2*   ttp     = (float2*)(os1 + N);                   // 2N floats

        hipMemsetAsync(cursors, 0, 256, stream);

        int ablocks = (E + ACHUNK - 1) / ACHUNK;
        int ng = (N + 255) / 256;

        bucketize_kernel<<<ablocks, BBLK, 0, stream>>>(src, dst, cursors, ebuf, E);
        b0_deg_kernel<<<NBK * R1REP, ABLK, 0, stream>>>(ebuf, cursors, (unsigned*)part);
        r0_kernel<<<ng, 256, 0, stream>>>((unsigned*)part, x, dinv, xd, N);
        b1_agg1_kernel<<<NBK * R1REP, ABLK, 0, stream>>>(ebuf, cursors, xd, part);
        r1_kernel<<<ng, 256, 0, stream>>>(part, x, dinv, W1, b1, W2, ttp, os0, os1, N);
        b2_agg2_kernel<<<NBK * R2REP, ABLK, 0, stream>>>(ebuf, cursors, ttp, part);
        r2_kernel<<<ng, 256, 0, stream>>>(part, dinv, os0, os1, b2, (float2*)out, N);
    } else {
        float* deg  = (float*)d_ws;
        float* dinv = deg + N;
        float* s1   = dinv + N;
        float* t0   = s1 + N;
        float* t1   = t0 + N;
        float* o0   = t1 + N;
        float* o1   = o0 + N;

        hipMemsetAsync(deg, 0, (size_t)N * sizeof(float), stream);
        int eg = (E + 255) / 256, ng = (N + 255) / 256;
        deg_kernel<<<eg, 256, 0, stream>>>(dst, deg, E);
        dinv_kernel<<<ng, 256, 0, stream>>>(deg, x, dinv, s1, N);
        agg1_kernel<<<eg, 256, 0, stream>>>(src, dst, x, dinv, s1, E);
        node_mlp_kernel<<<ng, 256, 0, stream>>>(s1, dinv, W1, b1, W2, t0, t1, o0, o1, N);
        agg2_kernel<<<eg, 256, 0, stream>>>(src, dst, dinv, t0, t1, o0, o1, E);
        logsoftmax_kernel<<<ng, 256, 0, stream>>>(o0, o1, b2, out, N);
    }
}